// Round 11
// baseline (2424.440 us; speedup 1.0000x reference)
//
#include <hip/hip_runtime.h>
#include <hip/hip_bf16.h>

#define T_LEN 2048
#define B_SZ  64
#define D_IN  64
#define H_SZ  128

typedef __attribute__((ext_vector_type(8))) _Float16 f16x8;
typedef __attribute__((ext_vector_type(4))) float    f32x4;

// pack 2 f32 -> 2 f16 (RTZ); residual captured by the lo term.
__device__ __forceinline__ unsigned pkrtz(float a, float b) {
    auto h = __builtin_amdgcn_cvt_pkrtz(a, b);
    union { decltype(h) h2; unsigned u; } c; c.h2 = h; return c.u;
}
__device__ __forceinline__ float f16lo(unsigned u) {
    union { unsigned short s; _Float16 h; } c; c.s = (unsigned short)(u & 0xffffu); return (float)c.h;
}
__device__ __forceinline__ float f16hi(unsigned u) {
    union { unsigned short s; _Float16 h; } c; c.s = (unsigned short)(u >> 16); return (float)c.h;
}
union F16P { unsigned u[4]; f16x8 v; };

// split 8 f32 (two float4, k-contiguous) into f16 hi + lo fragments.
__device__ __forceinline__ void split8(float4 a, float4 b, f16x8& hi, f16x8& lo) {
    F16P H, L;
    H.u[0] = pkrtz(a.x, a.y);
    H.u[1] = pkrtz(a.z, a.w);
    H.u[2] = pkrtz(b.x, b.y);
    H.u[3] = pkrtz(b.z, b.w);
    L.u[0] = pkrtz(a.x - f16lo(H.u[0]), a.y - f16hi(H.u[0]));
    L.u[1] = pkrtz(a.z - f16lo(H.u[1]), a.w - f16hi(H.u[1]));
    L.u[2] = pkrtz(b.x - f16lo(H.u[2]), b.y - f16hi(H.u[2]));
    L.u[3] = pkrtz(b.z - f16lo(H.u[3]), b.w - f16hi(H.u[3]));
    hi = H.v; lo = L.v;
}

// ---------------------------------------------------------------------------
// Kernel 1: collapse fc1+fc2 into w_eff[256], b_eff.
// ws layout (floats): [0..255]=w_eff, [256]=b_eff, [512..]=partials, then xp
// ---------------------------------------------------------------------------
__global__ __launch_bounds__(256)
void prep_kernel(const float* __restrict__ fc1_W, const float* __restrict__ fc1_b,
                 const float* __restrict__ fc2_W, const float* __restrict__ fc2_b,
                 float* __restrict__ ws)
{
    const int i = threadIdx.x;  // 0..255
    float s = 0.0f;
    #pragma unroll 4
    for (int o = 0; o < 128; ++o) s = fmaf(fc2_W[o], fc1_W[o * 256 + i], s);
    ws[i] = s;

    __shared__ float red[128];
    if (i < 128) red[i] = fc2_W[i] * fc1_b[i];
    __syncthreads();
    if (i == 0) {
        float b = fc2_b[0];
        for (int o = 0; o < 128; ++o) b += red[o];
        ws[256] = b;
    }
}

// ---------------------------------------------------------------------------
// Kernel 1b (v3-jt, proven r10): xp[(dir*64+b)][j][t] = x·Wih^T + bih + bhh.
// ---------------------------------------------------------------------------
__global__ __launch_bounds__(256, 2)
void xp_gemm(const float* __restrict__ x,
             const float* __restrict__ Wih_f, const float* __restrict__ bih_f,
             const float* __restrict__ bhh_f,
             const float* __restrict__ Wih_b, const float* __restrict__ bih_b,
             const float* __restrict__ bhh_b,
             float* __restrict__ xp)
{
    const int blk = blockIdx.x;
    const int dir = blk >> 11;
    const int b   = (blk >> 5) & 63;
    const int tc  = blk & 31;
    const int tid = threadIdx.x;

    const float* __restrict__ Wih = dir ? Wih_b : Wih_f;
    const float* __restrict__ bih = dir ? bih_b : bih_f;
    const float* __restrict__ bhh = dir ? bhh_b : bhh_f;

    __shared__ __align__(16) float xs[64][68];
    __shared__ __align__(16) float wsd[128][68];
    __shared__ float bs[128];

    {
        const float4* src = (const float4*)(x + ((size_t)b * T_LEN + tc * 64) * D_IN);
        #pragma unroll
        for (int r = 0; r < 4; ++r) {
            int qq = tid + 256 * r;
            float4 v = src[qq];
            *(float4*)&xs[qq >> 4][(qq & 15) * 4] = v;
        }
        const float4* wsrc = (const float4*)Wih;
        #pragma unroll
        for (int r = 0; r < 8; ++r) {
            int qq = tid + 256 * r;
            float4 v = wsrc[qq];
            *(float4*)&wsd[qq >> 4][(qq & 15) * 4] = v;
        }
        if (tid < 128) bs[tid] = bih[tid] + bhh[tid];
    }
    __syncthreads();

    const int tg = tid & 15;   // t = tc*64 + tg + 16*tt
    const int jg = tid >> 4;   // j = jg + 16*jj

    float acc[8][4];
    #pragma unroll
    for (int jj = 0; jj < 8; ++jj)
        #pragma unroll
        for (int tt = 0; tt < 4; ++tt) acc[jj][tt] = 0.0f;

    #pragma unroll 2
    for (int kc = 0; kc < 16; ++kc) {
        float4 xv[4];
        #pragma unroll
        for (int tt = 0; tt < 4; ++tt)
            xv[tt] = *(const float4*)&xs[tg + 16 * tt][kc * 4];
        #pragma unroll
        for (int jj = 0; jj < 8; ++jj) {
            float4 wv = *(const float4*)&wsd[jg + 16 * jj][kc * 4];
            #pragma unroll
            for (int tt = 0; tt < 4; ++tt) {
                acc[jj][tt] = fmaf(wv.x, xv[tt].x, acc[jj][tt]);
                acc[jj][tt] = fmaf(wv.y, xv[tt].y, acc[jj][tt]);
                acc[jj][tt] = fmaf(wv.z, xv[tt].z, acc[jj][tt]);
                acc[jj][tt] = fmaf(wv.w, xv[tt].w, acc[jj][tt]);
            }
        }
    }

    float* xpo = xp + (size_t)(dir * 64 + b) * H_SZ * T_LEN + tc * 64 + tg;
    #pragma unroll
    for (int jj = 0; jj < 8; ++jj) {
        const float bj = bs[jg + 16 * jj];
        #pragma unroll
        for (int tt = 0; tt < 4; ++tt)
            xpo[(size_t)(jg + 16 * jj) * T_LEN + 16 * tt] = acc[jj][tt] + bj;
    }
}

// DPP add: v += dpp_moved(v); bound_ctrl=true -> invalid source lanes give 0.
#define DPP_ADD_F32(v, ctrl)                                                   \
    v += __int_as_float(__builtin_amdgcn_update_dpp(                           \
            0, __float_as_int(v), (ctrl), 0xf, 0xf, true))

// Relaxed barrier: lgkmcnt(0) (ds visibility) without the vmcnt(0) drain.
__device__ __forceinline__ void chain_barrier() {
    asm volatile("s_waitcnt lgkmcnt(0)" ::: "memory");
    __builtin_amdgcn_s_barrier();
    asm volatile("" ::: "memory");
}
__device__ __forceinline__ void chain_barrier_strict() {
    asm volatile("s_waitcnt lgkmcnt(0)" ::: "memory");
    __builtin_amdgcn_s_barrier();
    __builtin_amdgcn_sched_barrier(0);
}

// ---------------------------------------------------------------------------
// Kernel 2 (MFMA): per step, H[16x128] = relu(XP_t + H_prev @ Whh^T) as a
// batched 16x16x32 f16 MFMA GEMM (hi/lo split, 3 terms ~ fp32 accuracy).
// 8 blocks = 2 dir x 4 batch-blocks of 16; 4 waves; wave w owns col-tiles
// 32w and 32w+16. A (=H) read from LDS fp32 [16][132]; B (=Whh^T) constant
// in registers. k-slot order is identical for A and B by construction, so
// any HW k-permutation cancels in the dot product; only the verified C/D
// mapping (col=lane&15, row=4*(lane>>4)+reg) is load-bearing.
// p partials DPP-row-reduced into a 2-bank LDS buffer, flushed every 16
// steps as coalesced stores (2 partials per (b,t): one per direction).
// ---------------------------------------------------------------------------
template<int DIR>
__device__ __forceinline__
void mfma_chain(const float* __restrict__ xp, const float* __restrict__ Whh,
                const float* __restrict__ weff, float* __restrict__ part,
                int bb, float (*Hb)[16][132], float (*PB)[4][16][16])
{
    const int tid = threadIdx.x;
    const int w = tid >> 6, l = tid & 63, g = l >> 4, q = l & 15;
    const int n0 = 32 * w + q, n1 = n0 + 16;

    // B fragments: Bh/Bl[tau][kc]; slot i <-> k = kc*32 + 8*g + i
    f16x8 Bh[2][4], Bl[2][4];
    #pragma unroll
    for (int tau = 0; tau < 2; ++tau) {
        const int n = 32 * w + 16 * tau + q;
        #pragma unroll
        for (int kc = 0; kc < 4; ++kc) {
            float4 va = *(const float4*)(Whh + n * H_SZ + kc * 32 + 8 * g);
            float4 vb = *(const float4*)(Whh + n * H_SZ + kc * 32 + 8 * g + 4);
            split8(va, vb, Bh[tau][kc], Bl[tau][kc]);
        }
    }
    const float wv0 = weff[DIR * H_SZ + n0];
    const float wv1 = weff[DIR * H_SZ + n1];

    // xp stream pointers: idx = tau*4+reg ; batch = bb*16 + 4g + reg
    const float* xq[8];
    #pragma unroll
    for (int tau = 0; tau < 2; ++tau)
        #pragma unroll
        for (int reg = 0; reg < 4; ++reg) {
            const int bat = bb * 16 + 4 * g + reg;
            const int n = 32 * w + 16 * tau + q;
            xq[tau * 4 + reg] = xp + ((size_t)(DIR * 64 + bat) * H_SZ + n) * (size_t)T_LEN;
        }

    float XA[8], XB[8];
    {
        const int ta = DIR ? (T_LEN - 1) : 0;
        const int tb = DIR ? (T_LEN - 2) : 1;
        #pragma unroll
        for (int i = 0; i < 8; ++i) { XA[i] = xq[i][ta]; XB[i] = xq[i][tb]; }
    }

#define MSTEP(SS, P, XC) do {                                                  \
    float4 ar[8];                                                              \
    _Pragma("unroll") for (int kc = 0; kc < 4; ++kc) {                         \
        ar[2*kc]   = *(const float4*)&Hb[P][q][kc * 32 + 8 * g];               \
        ar[2*kc+1] = *(const float4*)&Hb[P][q][kc * 32 + 8 * g + 4];           \
    }                                                                          \
    float xv[8];                                                               \
    _Pragma("unroll") for (int i = 0; i < 8; ++i) xv[i] = XC[i];               \
    {   /* refill this bank for step s+2 */                                    \
        int sp = (SS) + 2; sp = (sp < T_LEN) ? sp : (T_LEN - 1);               \
        const int tp = DIR ? (T_LEN - 1 - sp) : sp;                            \
        _Pragma("unroll") for (int i = 0; i < 8; ++i) XC[i] = xq[i][tp];       \
    }                                                                          \
    f16x8 Ah[4], Al[4];                                                        \
    _Pragma("unroll") for (int kc = 0; kc < 4; ++kc)                           \
        split8(ar[2*kc], ar[2*kc+1], Ah[kc], Al[kc]);                          \
    f32x4 C0 = {0.f, 0.f, 0.f, 0.f}, C1 = {0.f, 0.f, 0.f, 0.f};                \
    _Pragma("unroll") for (int kc = 0; kc < 4; ++kc) {                         \
        C0 = __builtin_amdgcn_mfma_f32_16x16x32_f16(Ah[kc], Bh[0][kc], C0, 0, 0, 0); \
        C1 = __builtin_amdgcn_mfma_f32_16x16x32_f16(Ah[kc], Bh[1][kc], C1, 0, 0, 0); \
        C0 = __builtin_amdgcn_mfma_f32_16x16x32_f16(Ah[kc], Bl[0][kc], C0, 0, 0, 0); \
        C1 = __builtin_amdgcn_mfma_f32_16x16x32_f16(Ah[kc], Bl[1][kc], C1, 0, 0, 0); \
        C0 = __builtin_amdgcn_mfma_f32_16x16x32_f16(Al[kc], Bh[0][kc], C0, 0, 0, 0); \
        C1 = __builtin_amdgcn_mfma_f32_16x16x32_f16(Al[kc], Bh[1][kc], C1, 0, 0, 0); \
    }                                                                          \
    float hs[8];                                                               \
    _Pragma("unroll") for (int reg = 0; reg < 4; ++reg) {                      \
        float h0 = fmaxf(C0[reg] + xv[reg],     0.0f);                         \
        float h1 = fmaxf(C1[reg] + xv[4 + reg], 0.0f);                         \
        Hb[(P) ^ 1][4 * g + reg][n0] = h0;                                     \
        Hb[(P) ^ 1][4 * g + reg][n1] = h1;                                     \
        hs[reg] = h0; hs[4 + reg] = h1;                                        \
    }                                                                          \
    float pv0 = fmaf(wv0, hs[0], wv1 * hs[4]);                                 \
    float pv1 = fmaf(wv0, hs[1], wv1 * hs[5]);                                 \
    float pv2 = fmaf(wv0, hs[2], wv1 * hs[6]);                                 \
    float pv3 = fmaf(wv0, hs[3], wv1 * hs[7]);                                 \
    DPP_ADD_F32(pv0, 0x111); DPP_ADD_F32(pv1, 0x111);                          \
    DPP_ADD_F32(pv2, 0x111); DPP_ADD_F32(pv3, 0x111);                          \
    DPP_ADD_F32(pv0, 0x112); DPP_ADD_F32(pv1, 0x112);                          \
    DPP_ADD_F32(pv2, 0x112); DPP_ADD_F32(pv3, 0x112);                          \
    DPP_ADD_F32(pv0, 0x114); DPP_ADD_F32(pv1, 0x114);                          \
    DPP_ADD_F32(pv2, 0x114); DPP_ADD_F32(pv3, 0x114);                          \
    DPP_ADD_F32(pv0, 0x118); DPP_ADD_F32(pv1, 0x118);                          \
    DPP_ADD_F32(pv2, 0x118); DPP_ADD_F32(pv3, 0x118);                          \
    if (q == 15) {                                                             \
        const int ts_ = (SS) & 15, pb_ = ((SS) >> 4) & 1;                      \
        PB[pb_][w][4 * g + 0][ts_] = pv0;                                      \
        PB[pb_][w][4 * g + 1][ts_] = pv1;                                      \
        PB[pb_][w][4 * g + 2][ts_] = pv2;                                      \
        PB[pb_][w][4 * g + 3][ts_] = pv3;                                      \
    }                                                                          \
    chain_barrier();                                                           \
} while (0)

#define PFLUSH(SB) do {                                                        \
    const int pb_ = ((SB) >> 4) & 1;                                           \
    const int ts_ = tid & 15, bq_ = tid >> 4;                                  \
    float s4 = PB[pb_][0][bq_][ts_] + PB[pb_][1][bq_][ts_]                     \
             + PB[pb_][2][bq_][ts_] + PB[pb_][3][bq_][ts_];                    \
    const int sg_ = (SB) + ts_;                                                \
    const int tg_ = DIR ? (T_LEN - 1 - sg_) : sg_;                             \
    part[((size_t)(DIR * 64 + bb * 16 + bq_)) * T_LEN + tg_] = s4;             \
} while (0)

    #pragma unroll 1
    for (int s = 0; s < T_LEN; s += 2) {
        if ((s & 15) == 0 && s > 0) PFLUSH(s - 16);
        MSTEP(s,     0, XA);
        MSTEP(s + 1, 1, XB);
    }
    PFLUSH(T_LEN - 16);

#undef MSTEP
#undef PFLUSH
}

__global__ __launch_bounds__(256, 1)
void brnn_recur_mfma(const float* __restrict__ xp,
                     const float* __restrict__ Whh_f, const float* __restrict__ Whh_b,
                     const float* __restrict__ weff,  float* __restrict__ part)
{
    __shared__ __align__(16) float Hb[2][16][132];   // fp32 H, double-buffered
    __shared__ __align__(16) float PB[2][4][16][16]; // p partials [bank][w][b][ts]
    const int dir = blockIdx.x >> 2;
    const int bb  = blockIdx.x & 3;
    for (int i = threadIdx.x; i < 2 * 16 * 132; i += 256) ((float*)Hb)[i] = 0.0f;
    __syncthreads();
    if (dir == 0) mfma_chain<0>(xp, Whh_f, weff, part, bb, Hb, PB);
    else          mfma_chain<1>(xp, Whh_b, weff, part, bb, Hb, PB);
}

// ---------------------------------------------------------------------------
// Fallback recurrence (round-4 structure, x in-loop) for small ws_size.
// ---------------------------------------------------------------------------
__global__ __launch_bounds__(256, 1)
void brnn_recur_fb(const float* __restrict__ x,
                   const float* __restrict__ Wih_f, const float* __restrict__ Whh_f,
                   const float* __restrict__ bih_f, const float* __restrict__ bhh_f,
                   const float* __restrict__ Wih_b, const float* __restrict__ Whh_b,
                   const float* __restrict__ bih_b, const float* __restrict__ bhh_b,
                   const float* __restrict__ weff,  float* __restrict__ partbuf)
{
    const int blk  = blockIdx.x;
    const int dir  = blk >> 6;
    const int b    = blk & 63;
    const int tid  = threadIdx.x;
    const int w    = tid >> 6;
    const int l    = tid & 63;
    const int g    = l & 7;
    const int m    = l >> 3;
    const int j0   = w * 32 + m * 4;
    const bool wr  = (g == 7);

    const float* Wih = dir ? Wih_b : Wih_f;
    const float* Whh = dir ? Whh_b : Whh_f;
    const float* bih = dir ? bih_b : bih_f;
    const float* bhh = dir ? bhh_b : bhh_f;

    float whh[64];
    #pragma unroll
    for (int jj = 0; jj < 4; ++jj)
        #pragma unroll
        for (int i = 0; i < 4; ++i)
            ((float4*)whh)[jj * 4 + i] =
                *(const float4*)(Whh + (j0 + jj) * 128 + g * 16 + i * 4);
    float wih[32];
    #pragma unroll
    for (int jj = 0; jj < 4; ++jj)
        #pragma unroll
        for (int i = 0; i < 2; ++i)
            ((float4*)wih)[jj * 2 + i] =
                *(const float4*)(Wih + (j0 + jj) * 64 + g * 8 + i * 4);

    float4 b4 = make_float4(0.f, 0.f, 0.f, 0.f);
    if (g == 0) {
        float4 bi = *(const float4*)(bih + j0);
        float4 bh = *(const float4*)(bhh + j0);
        b4 = make_float4(bi.x + bh.x, bi.y + bh.y, bi.z + bh.z, bi.w + bh.w);
    }
    const float4 w4 = *(const float4*)(weff + dir * 128 + j0);

    __shared__ __align__(16) float hbuf[2][160];
    if (tid < 160) hbuf[0][tid] = 0.0f;
    __syncthreads();

    const float* xbase = x + (size_t)b * T_LEN * D_IN + g * 8;
    float* pout = partbuf + ((size_t)blk * 4 + w) * T_LEN;

    float xq0[8], xq1[8], xq2[8], xq3[8];
    {
        const float4* xp0 = (const float4*)(xbase + (size_t)(dir ? (T_LEN - 1) : 0) * D_IN);
        ((float4*)xq0)[0] = xp0[0];
        ((float4*)xq0)[1] = xp0[1];
        const float4* xp1 = (const float4*)(xbase + (size_t)(dir ? (T_LEN - 2) : 1) * D_IN);
        ((float4*)xq1)[0] = xp1[0];
        ((float4*)xq1)[1] = xp1[1];
    }

    float p_carry = 0.0f;
    int   t_prev  = 0;
    const int hwidx = 40 * w + 4 * m + 4 * (m >> 2);

#define STEP(S, RD, XCUR, XPRE) do {                                           \
        const int s_  = (S);                                                   \
        if (s_ > 0) {                                                          \
            float pr_ = p_carry;                                               \
            DPP_ADD_F32(pr_, 0x118); DPP_ADD_F32(pr_, 0x142);                  \
            DPP_ADD_F32(pr_, 0x143);                                           \
            if (l == 63) pout[t_prev] = pr_;                                   \
        }                                                                      \
        {                                                                      \
            const int sp_ = (s_ + 2 < T_LEN) ? (s_ + 2) : (T_LEN - 1);         \
            const int tp_ = dir ? (T_LEN - 1 - sp_) : sp_;                     \
            const float4* xp_ = (const float4*)(xbase + (size_t)tp_ * D_IN);   \
            ((float4*)XPRE)[0] = xp_[0];                                       \
            ((float4*)XPRE)[1] = xp_[1];                                       \
        }                                                                      \
        const float4* hp_ = (const float4*)&hbuf[RD][20 * g];                  \
        float4 hv_[4];                                                         \
        _Pragma("unroll") for (int i = 0; i < 4; ++i) hv_[i] = hp_[i];         \
        float a0 = b4.x, a1 = b4.y, a2 = b4.z, a3 = b4.w;                      \
        _Pragma("unroll") for (int i = 0; i < 8; ++i) {                        \
            a0 = fmaf(wih[0 * 8 + i], XCUR[i], a0);                            \
            a1 = fmaf(wih[1 * 8 + i], XCUR[i], a1);                            \
            a2 = fmaf(wih[2 * 8 + i], XCUR[i], a2);                            \
            a3 = fmaf(wih[3 * 8 + i], XCUR[i], a3);                            \
        }                                                                      \
        _Pragma("unroll") for (int i = 0; i < 4; ++i) {                        \
            const float* hq_ = (const float*)&hv_[i];                          \
            _Pragma("unroll") for (int c = 0; c < 4; ++c) {                    \
                a0 = fmaf(whh[0 * 16 + i * 4 + c], hq_[c], a0);                \
                a1 = fmaf(whh[1 * 16 + i * 4 + c], hq_[c], a1);                \
                a2 = fmaf(whh[2 * 16 + i * 4 + c], hq_[c], a2);                \
                a3 = fmaf(whh[3 * 16 + i * 4 + c], hq_[c], a3);                \
            }                                                                  \
        }                                                                      \
        DPP_ADD_F32(a0, 0x111); DPP_ADD_F32(a1, 0x111);                        \
        DPP_ADD_F32(a2, 0x111); DPP_ADD_F32(a3, 0x111);                        \
        DPP_ADD_F32(a0, 0x112); DPP_ADD_F32(a1, 0x112);                        \
        DPP_ADD_F32(a2, 0x112); DPP_ADD_F32(a3, 0x112);                        \
        DPP_ADD_F32(a0, 0x114); DPP_ADD_F32(a1, 0x114);                        \
        DPP_ADD_F32(a2, 0x114); DPP_ADD_F32(a3, 0x114);                        \
        float4 h4_;                                                            \
        h4_.x = fmaxf(a0, 0.0f); h4_.y = fmaxf(a1, 0.0f);                      \
        h4_.z = fmaxf(a2, 0.0f); h4_.w = fmaxf(a3, 0.0f);                      \
        p_carry = 0.0f;                                                        \
        if (wr) {                                                              \
            *(float4*)&hbuf[(RD) ^ 1][hwidx] = h4_;                            \
            p_carry = w4.x * h4_.x + w4.y * h4_.y                              \
                    + w4.z * h4_.z + w4.w * h4_.w;                             \
        }                                                                      \
        t_prev = dir ? (T_LEN - 1 - s_) : s_;                                  \
        chain_barrier_strict();                                                \
    } while (0)

    #pragma unroll 1
    for (int s = 0; s < T_LEN; s += 4) {
        STEP(s,     0, xq0, xq2);
        STEP(s + 1, 1, xq1, xq3);
        STEP(s + 2, 0, xq2, xq0);
        STEP(s + 3, 1, xq3, xq1);
    }
#undef STEP

    {
        float pr = p_carry;
        DPP_ADD_F32(pr, 0x118); DPP_ADD_F32(pr, 0x142); DPP_ADD_F32(pr, 0x143);
        if (l == 63) pout[t_prev] = pr;
    }
}

// ---------------------------------------------------------------------------
// Kernel 3a (mfma path): logits from 2 partials (one per direction) + lsm.
// ---------------------------------------------------------------------------
__global__ __launch_bounds__(256)
void brnn_lsm2(const float* __restrict__ part, const float* __restrict__ ws,
               float* __restrict__ out)
{
    const int b   = blockIdx.x;
    const int tid = threadIdx.x;
    __shared__ float lg[T_LEN];
    __shared__ float red[8];

    const float beff = ws[256];

    float lmax = -3.0e38f;
    for (int t = tid; t < T_LEN; t += 256) {
        float s = beff + part[(size_t)b * T_LEN + t]
                       + part[(size_t)(64 + b) * T_LEN + t];
        lg[t] = s;
        lmax = fmaxf(lmax, s);
    }
    #pragma unroll
    for (int mm = 1; mm <= 32; mm <<= 1) lmax = fmaxf(lmax, __shfl_xor(lmax, mm));
    if ((tid & 63) == 0) red[tid >> 6] = lmax;
    __syncthreads();
    const float bmax = fmaxf(fmaxf(red[0], red[1]), fmaxf(red[2], red[3]));

    float lsum = 0.0f;
    for (int t = tid; t < T_LEN; t += 256) lsum += expf(lg[t] - bmax);
    #pragma unroll
    for (int mm = 1; mm <= 32; mm <<= 1) lsum += __shfl_xor(lsum, mm);
    if ((tid & 63) == 0) red[4 + (tid >> 6)] = lsum;
    __syncthreads();
    const float lse = bmax + logf(red[4] + red[5] + red[6] + red[7]);

    for (int t = tid; t < T_LEN; t += 256)
        out[(size_t)b * T_LEN + t] = lg[t] - lse;
}

// ---------------------------------------------------------------------------
// Kernel 3b (fallback path): logits from 8 partials + lsm.
// ---------------------------------------------------------------------------
__global__ __launch_bounds__(256)
void brnn_lsm8(const float* __restrict__ partbuf, const float* __restrict__ ws,
               float* __restrict__ out)
{
    const int b   = blockIdx.x;
    const int tid = threadIdx.x;
    __shared__ float lg[T_LEN];
    __shared__ float red[8];

    const float beff = ws[256];

    float lmax = -3.0e38f;
    for (int t = tid; t < T_LEN; t += 256) {
        float s = beff;
        #pragma unroll
        for (int dw = 0; dw < 8; ++dw) {
            const int dir = dw >> 2, wv = dw & 3;
            s += partbuf[(((size_t)(dir * 64 + b)) * 4 + wv) * T_LEN + t];
        }
        lg[t] = s;
        lmax = fmaxf(lmax, s);
    }
    #pragma unroll
    for (int mm = 1; mm <= 32; mm <<= 1) lmax = fmaxf(lmax, __shfl_xor(lmax, mm));
    if ((tid & 63) == 0) red[tid >> 6] = lmax;
    __syncthreads();
    const float bmax = fmaxf(fmaxf(red[0], red[1]), fmaxf(red[2], red[3]));

    float lsum = 0.0f;
    for (int t = tid; t < T_LEN; t += 256) lsum += expf(lg[t] - bmax);
    #pragma unroll
    for (int mm = 1; mm <= 32; mm <<= 1) lsum += __shfl_xor(lsum, mm);
    if ((tid & 63) == 0) red[4 + (tid >> 6)] = lsum;
    __syncthreads();
    const float lse = bmax + logf(red[4] + red[5] + red[6] + red[7]);

    for (int t = tid; t < T_LEN; t += 256)
        out[(size_t)b * T_LEN + t] = lg[t] - lse;
}

// ---------------------------------------------------------------------------
extern "C" void kernel_launch(void* const* d_in, const int* in_sizes, int n_in,
                              void* d_out, int out_size, void* d_ws, size_t ws_size,
                              hipStream_t stream)
{
    const float* x     = (const float*)d_in[0];
    const float* Wih_f = (const float*)d_in[1];
    const float* Whh_f = (const float*)d_in[2];
    const float* bih_f = (const float*)d_in[3];
    const float* bhh_f = (const float*)d_in[4];
    const float* Wih_b = (const float*)d_in[5];
    const float* Whh_b = (const float*)d_in[6];
    const float* bih_b = (const float*)d_in[7];
    const float* bhh_b = (const float*)d_in[8];
    const float* fc1_W = (const float*)d_in[9];
    const float* fc1_b = (const float*)d_in[10];
    const float* fc2_W = (const float*)d_in[11];
    const float* fc2_b = (const float*)d_in[12];
    float* out = (float*)d_out;

    float* wsf = (float*)d_ws;
    const size_t part_off   = 512;
    const size_t part_elems = (size_t)2 * 64 * 4 * T_LEN;          // 1 Mi floats
    const size_t xp_off     = part_off + part_elems;
    const size_t xp_elems   = (size_t)2 * 64 * T_LEN * H_SZ;       // 32 Mi floats
    float* part = wsf + part_off;
    float* xpbf = wsf + xp_off;
    const bool big_ws = ws_size >= (xp_off + xp_elems) * sizeof(float);

    hipLaunchKernelGGL(prep_kernel, dim3(1), dim3(256), 0, stream,
                       fc1_W, fc1_b, fc2_W, fc2_b, wsf);
    if (big_ws) {
        hipLaunchKernelGGL(xp_gemm, dim3(4096), dim3(256), 0, stream,
                           x, Wih_f, bih_f, bhh_f, Wih_b, bih_b, bhh_b, xpbf);
        hipLaunchKernelGGL(brnn_recur_mfma, dim3(8), dim3(256), 0, stream,
                           xpbf, Whh_f, Whh_b, wsf, part);
        hipLaunchKernelGGL(brnn_lsm2, dim3(64), dim3(256), 0, stream,
                           part, wsf, out);
    } else {
        hipLaunchKernelGGL(brnn_recur_fb, dim3(128), dim3(256), 0, stream,
                           x, Wih_f, Whh_f, bih_f, bhh_f,
                           Wih_b, Whh_b, bih_b, bhh_b, wsf, part);
        hipLaunchKernelGGL(brnn_lsm8, dim3(64), dim3(256), 0, stream,
                           part, wsf, out);
    }
}

// Round 12
// 1944.192 us; speedup vs baseline: 1.2470x; 1.2470x over previous
//
#include <hip/hip_runtime.h>
#include <hip/hip_bf16.h>

#define T_LEN 2048
#define B_SZ  64
#define D_IN  64
#define H_SZ  128

typedef float f32x2 __attribute__((ext_vector_type(2)));

// ---------------------------------------------------------------------------
// Kernel 1: collapse fc1+fc2 into w_eff[256], b_eff.
// ws layout (floats): [0..255]=w_eff, [256]=b_eff, [512..]=partials, then xp
// ---------------------------------------------------------------------------
__global__ __launch_bounds__(256)
void prep_kernel(const float* __restrict__ fc1_W, const float* __restrict__ fc1_b,
                 const float* __restrict__ fc2_W, const float* __restrict__ fc2_b,
                 float* __restrict__ ws)
{
    const int i = threadIdx.x;  // 0..255
    float s = 0.0f;
    #pragma unroll 4
    for (int o = 0; o < 128; ++o) s = fmaf(fc2_W[o], fc1_W[o * 256 + i], s);
    ws[i] = s;

    __shared__ float red[128];
    if (i < 128) red[i] = fc2_W[i] * fc1_b[i];
    __syncthreads();
    if (i == 0) {
        float b = fc2_b[0];
        for (int o = 0; o < 128; ++o) b += red[o];
        ws[256] = b;
    }
}

// ---------------------------------------------------------------------------
// Kernel 1b (v3-jt, proven r10): xp[(dir*64+b)][j][t] = x·Wih^T + bih + bhh.
// ---------------------------------------------------------------------------
__global__ __launch_bounds__(256, 2)
void xp_gemm(const float* __restrict__ x,
             const float* __restrict__ Wih_f, const float* __restrict__ bih_f,
             const float* __restrict__ bhh_f,
             const float* __restrict__ Wih_b, const float* __restrict__ bih_b,
             const float* __restrict__ bhh_b,
             float* __restrict__ xp)
{
    const int blk = blockIdx.x;
    const int dir = blk >> 11;
    const int b   = (blk >> 5) & 63;
    const int tc  = blk & 31;
    const int tid = threadIdx.x;

    const float* __restrict__ Wih = dir ? Wih_b : Wih_f;
    const float* __restrict__ bih = dir ? bih_b : bih_f;
    const float* __restrict__ bhh = dir ? bhh_b : bhh_f;

    __shared__ __align__(16) float xs[64][68];
    __shared__ __align__(16) float wsd[128][68];
    __shared__ float bs[128];

    {
        const float4* src = (const float4*)(x + ((size_t)b * T_LEN + tc * 64) * D_IN);
        #pragma unroll
        for (int r = 0; r < 4; ++r) {
            int qq = tid + 256 * r;
            float4 v = src[qq];
            *(float4*)&xs[qq >> 4][(qq & 15) * 4] = v;
        }
        const float4* wsrc = (const float4*)Wih;
        #pragma unroll
        for (int r = 0; r < 8; ++r) {
            int qq = tid + 256 * r;
            float4 v = wsrc[qq];
            *(float4*)&wsd[qq >> 4][(qq & 15) * 4] = v;
        }
        if (tid < 128) bs[tid] = bih[tid] + bhh[tid];
    }
    __syncthreads();

    const int tg = tid & 15;   // t = tc*64 + tg + 16*tt
    const int jg = tid >> 4;   // j = jg + 16*jj

    float acc[8][4];
    #pragma unroll
    for (int jj = 0; jj < 8; ++jj)
        #pragma unroll
        for (int tt = 0; tt < 4; ++tt) acc[jj][tt] = 0.0f;

    #pragma unroll 2
    for (int kc = 0; kc < 16; ++kc) {
        float4 xv[4];
        #pragma unroll
        for (int tt = 0; tt < 4; ++tt)
            xv[tt] = *(const float4*)&xs[tg + 16 * tt][kc * 4];
        #pragma unroll
        for (int jj = 0; jj < 8; ++jj) {
            float4 wv = *(const float4*)&wsd[jg + 16 * jj][kc * 4];
            #pragma unroll
            for (int tt = 0; tt < 4; ++tt) {
                acc[jj][tt] = fmaf(wv.x, xv[tt].x, acc[jj][tt]);
                acc[jj][tt] = fmaf(wv.y, xv[tt].y, acc[jj][tt]);
                acc[jj][tt] = fmaf(wv.z, xv[tt].z, acc[jj][tt]);
                acc[jj][tt] = fmaf(wv.w, xv[tt].w, acc[jj][tt]);
            }
        }
    }

    float* xpo = xp + (size_t)(dir * 64 + b) * H_SZ * T_LEN + tc * 64 + tg;
    #pragma unroll
    for (int jj = 0; jj < 8; ++jj) {
        const float bj = bs[jg + 16 * jj];
        #pragma unroll
        for (int tt = 0; tt < 4; ++tt)
            xpo[(size_t)(jg + 16 * jj) * T_LEN + 16 * tt] = acc[jj][tt] + bj;
    }
}

// DPP add: v += dpp_moved(v); bound_ctrl=true -> invalid source lanes give 0.
#define DPP_ADD_F32(v, ctrl)                                                   \
    v += __int_as_float(__builtin_amdgcn_update_dpp(                           \
            0, __float_as_int(v), (ctrl), 0xf, 0xf, true))

__device__ __forceinline__ void chain_barrier_strict() {
    asm volatile("s_waitcnt lgkmcnt(0)" ::: "memory");
    __builtin_amdgcn_s_barrier();
    __builtin_amdgcn_sched_barrier(0);
}

// h LDS layout: float k stored at index k + 4*(k>>4)  (80B row stride).
// Half kh occupies float idx [80*kh, 80*kh+80): its 4 groups start at banks
// {80kh+20u mod 32}; kh=0 vs kh=1 differ by bank 16 -> the two broadcast
// addresses per b128 read hit DIFFERENT banks -> conflict-free.

// ---------------------------------------------------------------------------
// Kernel 2 (single-wave): one WAVE per (dir,batch) chain -> NO s_barrier.
// 128 blocks x 64 threads. Lane l: jq = l&31 -> 4 outputs j0 = 4*jq;
// kh = l>>5 -> k-half [64*kh, 64*kh+64). Per step: 16 broadcast
// ds_read_b128 -> 128 v_pk_fma_f32 (via __builtin_elementwise_fma on f32x2)
// -> 4x shfl_xor(32) k-half combine -> +xp, relu -> b128 h write (lanes<32)
// -> p dot + 6-DPP reduce (x0.5, halves duplicated) -> burst store per 8.
// Write->read handoff ordered by the in-wave DS pipe + lgkmcnt (no barrier).
// ---------------------------------------------------------------------------
template<int DIR>
__device__ __forceinline__
void recur_sw(const float* __restrict__ xp, const float* __restrict__ Whh,
              const float* __restrict__ weff, float* __restrict__ part,
              int b, float (*hbuf)[160])
{
    const int l  = threadIdx.x & 63;
    const int jq = l & 31;
    const int kh = l >> 5;
    const int j0 = 4 * jq;

    // Whh rows j0..j0+3, cols 64*kh..+63 -> 256 regs as f32x2 pairs.
    // Enumeration: float4 #i covers k = 64*kh + 4i .. +3  (same as h reads).
    f32x2 wh2[128];
    #pragma unroll
    for (int jj = 0; jj < 4; ++jj)
        #pragma unroll
        for (int i = 0; i < 16; ++i) {
            float4 v = *(const float4*)(Whh + (j0 + jj) * H_SZ + 64 * kh + 4 * i);
            wh2[jj * 32 + 2 * i]     = f32x2{v.x, v.y};
            wh2[jj * 32 + 2 * i + 1] = f32x2{v.z, v.w};
        }

    const float4 w4 = *(const float4*)(weff + DIR * H_SZ + j0);

    const float4* rd0 = (const float4*)&hbuf[0][80 * kh];
    const float4* rd1 = (const float4*)&hbuf[1][80 * kh];
    const int widx = 4 * jq + 4 * (jq >> 2);   // = j0 + 4*(j0>>4)
    float* wp0 = &hbuf[0][widx];
    float* wp1 = &hbuf[1][widx];

    // xp streams for j0..j0+3 ([j][t] layout)
    const float* xq0 = xp + ((size_t)(DIR * 64 + b) * H_SZ + j0 + 0) * (size_t)T_LEN;
    const float* xq1 = xq0 + (size_t)T_LEN;
    const float* xq2 = xq0 + (size_t)2 * T_LEN;
    const float* xq3 = xq0 + (size_t)3 * T_LEN;

    float* pout = part + (size_t)(DIR * 64 + b) * T_LEN;
    float* pst  = pout + (DIR ? (T_LEN - 8) : 0);

    float4 X0, X1;
    {
        const int ta = DIR ? (T_LEN - 1) : 0;
        const int tb = DIR ? (T_LEN - 2) : 1;
        X0 = make_float4(xq0[ta], xq1[ta], xq2[ta], xq3[ta]);
        X1 = make_float4(xq0[tb], xq1[tb], xq2[tb], xq3[tb]);
    }

    float ps[8];

#define KSTEP(K, XC) do {                                                      \
        /* 1. h read: 16 broadcast b128 (2 distinct addrs/instr, diff banks)*/ \
        float4 hv[16];                                                         \
        if ((K) & 1) {                                                         \
            _Pragma("unroll") for (int u = 0; u < 4; ++u)                      \
                _Pragma("unroll") for (int i = 0; i < 4; ++i)                  \
                    hv[u * 4 + i] = rd1[5 * u + i];                            \
        } else {                                                               \
            _Pragma("unroll") for (int u = 0; u < 4; ++u)                      \
                _Pragma("unroll") for (int i = 0; i < 4; ++i)                  \
                    hv[u * 4 + i] = rd0[5 * u + i];                            \
        }                                                                      \
        const f32x2* h2 = (const f32x2*)hv;                                    \
        /* 2. 128 packed FMAs (256 MACs) */                                    \
        f32x2 c0 = {0.f, 0.f}, c1 = {0.f, 0.f};                                \
        f32x2 c2 = {0.f, 0.f}, c3 = {0.f, 0.f};                                \
        _Pragma("unroll") for (int kp = 0; kp < 32; ++kp) {                    \
            f32x2 hh = h2[kp];                                                 \
            c0 = __builtin_elementwise_fma(wh2[      kp], hh, c0);             \
            c1 = __builtin_elementwise_fma(wh2[32  + kp], hh, c1);             \
            c2 = __builtin_elementwise_fma(wh2[64  + kp], hh, c2);             \
            c3 = __builtin_elementwise_fma(wh2[96  + kp], hh, c3);             \
        }                                                                      \
        float a0 = c0.x + c0.y, a1 = c1.x + c1.y;                              \
        float a2 = c2.x + c2.y, a3 = c3.x + c3.y;                              \
        /* 3. combine k-halves (lane l <-> l^32) */                           \
        a0 += __shfl_xor(a0, 32); a1 += __shfl_xor(a1, 32);                    \
        a2 += __shfl_xor(a2, 32); a3 += __shfl_xor(a3, 32);                    \
        /* 4. + xp, relu */                                                    \
        float4 h4;                                                             \
        h4.x = fmaxf(a0 + XC.x, 0.0f); h4.y = fmaxf(a1 + XC.y, 0.0f);          \
        h4.z = fmaxf(a2 + XC.z, 0.0f); h4.w = fmaxf(a3 + XC.w, 0.0f);          \
        /* 5. h write from lanes < 32 (both halves hold identical h4) */       \
        if (l < 32) *(float4*)(((K) & 1) ? wp0 : wp1) = h4;                    \
        /* 6. refill xp slot for step s+2 */                                   \
        {                                                                      \
            int sp = sbase + (K) + 2;                                          \
            sp = (sp < T_LEN) ? sp : (T_LEN - 1);                              \
            const int tp = DIR ? (T_LEN - 1 - sp) : sp;                        \
            XC = make_float4(xq0[tp], xq1[tp], xq2[tp], xq3[tp]);              \
        }                                                                      \
        /* 7. p dot + full-wave DPP reduce (halves duplicate -> x0.5) */       \
        float pv = fmaf(w4.x, h4.x, fmaf(w4.y, h4.y,                           \
                   fmaf(w4.z, h4.z, w4.w * h4.w)));                            \
        DPP_ADD_F32(pv, 0x111); DPP_ADD_F32(pv, 0x112);                        \
        DPP_ADD_F32(pv, 0x114); DPP_ADD_F32(pv, 0x118);                        \
        DPP_ADD_F32(pv, 0x142); DPP_ADD_F32(pv, 0x143);                        \
        ps[K] = 0.5f * pv;                                                     \
        /* in-wave DS ordering: ensure write lands before next step's read */  \
        asm volatile("s_waitcnt lgkmcnt(0)" ::: "memory");                     \
    } while (0)

    #pragma unroll 1
    for (int it = 0; it < T_LEN / 8; ++it) {
        const int sbase = it * 8;
        KSTEP(0, X0); KSTEP(1, X1); KSTEP(2, X0); KSTEP(3, X1);
        KSTEP(4, X0); KSTEP(5, X1); KSTEP(6, X0); KSTEP(7, X1);
        if (l == 63) {
            float4 v0, v1;
            if (DIR) { v0 = make_float4(ps[7], ps[6], ps[5], ps[4]);
                       v1 = make_float4(ps[3], ps[2], ps[1], ps[0]); }
            else     { v0 = make_float4(ps[0], ps[1], ps[2], ps[3]);
                       v1 = make_float4(ps[4], ps[5], ps[6], ps[7]); }
            *(float4*)pst = v0; *(float4*)(pst + 4) = v1;
        }
        pst += DIR ? -8 : 8;
    }
#undef KSTEP
}

__global__ __launch_bounds__(64, 1)
void brnn_recur_sw(const float* __restrict__ xp,
                   const float* __restrict__ Whh_f, const float* __restrict__ Whh_b,
                   const float* __restrict__ weff,  float* __restrict__ part)
{
    __shared__ __align__(16) float hbuf[2][160];
    const int blk = blockIdx.x;
    const int dir = blk >> 6;
    const int b   = blk & 63;
    for (int i = threadIdx.x; i < 320; i += 64) ((float*)hbuf)[i] = 0.0f;
    asm volatile("s_waitcnt lgkmcnt(0)" ::: "memory");
    if (dir == 0) recur_sw<0>(xp, Whh_f, weff, part, b, hbuf);
    else          recur_sw<1>(xp, Whh_b, weff, part, b, hbuf);
}

// ---------------------------------------------------------------------------
// Fallback recurrence (round-4 structure, x in-loop) for small ws_size.
// ---------------------------------------------------------------------------
__global__ __launch_bounds__(256, 1)
void brnn_recur_fb(const float* __restrict__ x,
                   const float* __restrict__ Wih_f, const float* __restrict__ Whh_f,
                   const float* __restrict__ bih_f, const float* __restrict__ bhh_f,
                   const float* __restrict__ Wih_b, const float* __restrict__ Whh_b,
                   const float* __restrict__ bih_b, const float* __restrict__ bhh_b,
                   const float* __restrict__ weff,  float* __restrict__ partbuf)
{
    const int blk  = blockIdx.x;
    const int dir  = blk >> 6;
    const int b    = blk & 63;
    const int tid  = threadIdx.x;
    const int w    = tid >> 6;
    const int l    = tid & 63;
    const int g    = l & 7;
    const int m    = l >> 3;
    const int j0   = w * 32 + m * 4;
    const bool wr  = (g == 7);

    const float* Wih = dir ? Wih_b : Wih_f;
    const float* Whh = dir ? Whh_b : Whh_f;
    const float* bih = dir ? bih_b : bih_f;
    const float* bhh = dir ? bhh_b : bhh_f;

    float whh[64];
    #pragma unroll
    for (int jj = 0; jj < 4; ++jj)
        #pragma unroll
        for (int i = 0; i < 4; ++i)
            ((float4*)whh)[jj * 4 + i] =
                *(const float4*)(Whh + (j0 + jj) * 128 + g * 16 + i * 4);
    float wih[32];
    #pragma unroll
    for (int jj = 0; jj < 4; ++jj)
        #pragma unroll
        for (int i = 0; i < 2; ++i)
            ((float4*)wih)[jj * 2 + i] =
                *(const float4*)(Wih + (j0 + jj) * 64 + g * 8 + i * 4);

    float4 b4 = make_float4(0.f, 0.f, 0.f, 0.f);
    if (g == 0) {
        float4 bi = *(const float4*)(bih + j0);
        float4 bh = *(const float4*)(bhh + j0);
        b4 = make_float4(bi.x + bh.x, bi.y + bh.y, bi.z + bh.z, bi.w + bh.w);
    }
    const float4 w4 = *(const float4*)(weff + dir * 128 + j0);

    __shared__ __align__(16) float hbuf[2][160];
    if (tid < 160) hbuf[0][tid] = 0.0f;
    __syncthreads();

    const float* xbase = x + (size_t)b * T_LEN * D_IN + g * 8;
    float* pout = partbuf + ((size_t)blk * 4 + w) * T_LEN;

    float xq0[8], xq1[8], xq2[8], xq3[8];
    {
        const float4* xp0 = (const float4*)(xbase + (size_t)(dir ? (T_LEN - 1) : 0) * D_IN);
        ((float4*)xq0)[0] = xp0[0];
        ((float4*)xq0)[1] = xp0[1];
        const float4* xp1 = (const float4*)(xbase + (size_t)(dir ? (T_LEN - 2) : 1) * D_IN);
        ((float4*)xq1)[0] = xp1[0];
        ((float4*)xq1)[1] = xp1[1];
    }

    float p_carry = 0.0f;
    int   t_prev  = 0;
    const int hwidx = 40 * w + 4 * m + 4 * (m >> 2);

#define STEP(S, RD, XCUR, XPRE) do {                                           \
        const int s_  = (S);                                                   \
        if (s_ > 0) {                                                          \
            float pr_ = p_carry;                                               \
            DPP_ADD_F32(pr_, 0x118); DPP_ADD_F32(pr_, 0x142);                  \
            DPP_ADD_F32(pr_, 0x143);                                           \
            if (l == 63) pout[t_prev] = pr_;                                   \
        }                                                                      \
        {                                                                      \
            const int sp_ = (s_ + 2 < T_LEN) ? (s_ + 2) : (T_LEN - 1);         \
            const int tp_ = dir ? (T_LEN - 1 - sp_) : sp_;                     \
            const float4* xp_ = (const float4*)(xbase + (size_t)tp_ * D_IN);   \
            ((float4*)XPRE)[0] = xp_[0];                                       \
            ((float4*)XPRE)[1] = xp_[1];                                       \
        }                                                                      \
        const float4* hp_ = (const float4*)&hbuf[RD][20 * g];                  \
        float4 hv_[4];                                                         \
        _Pragma("unroll") for (int i = 0; i < 4; ++i) hv_[i] = hp_[i];         \
        float a0 = b4.x, a1 = b4.y, a2 = b4.z, a3 = b4.w;                      \
        _Pragma("unroll") for (int i = 0; i < 8; ++i) {                        \
            a0 = fmaf(wih[0 * 8 + i], XCUR[i], a0);                            \
            a1 = fmaf(wih[1 * 8 + i], XCUR[i], a1);                            \
            a2 = fmaf(wih[2 * 8 + i], XCUR[i], a2);                            \
            a3 = fmaf(wih[3 * 8 + i], XCUR[i], a3);                            \
        }                                                                      \
        _Pragma("unroll") for (int i = 0; i < 4; ++i) {                        \
            const float* hq_ = (const float*)&hv_[i];                          \
            _Pragma("unroll") for (int c = 0; c < 4; ++c) {                    \
                a0 = fmaf(whh[0 * 16 + i * 4 + c], hq_[c], a0);                \
                a1 = fmaf(whh[1 * 16 + i * 4 + c], hq_[c], a1);                \
                a2 = fmaf(whh[2 * 16 + i * 4 + c], hq_[c], a2);                \
                a3 = fmaf(whh[3 * 16 + i * 4 + c], hq_[c], a3);                \
            }                                                                  \
        }                                                                      \
        DPP_ADD_F32(a0, 0x111); DPP_ADD_F32(a1, 0x111);                        \
        DPP_ADD_F32(a2, 0x111); DPP_ADD_F32(a3, 0x111);                        \
        DPP_ADD_F32(a0, 0x112); DPP_ADD_F32(a1, 0x112);                        \
        DPP_ADD_F32(a2, 0x112); DPP_ADD_F32(a3, 0x112);                        \
        DPP_ADD_F32(a0, 0x114); DPP_ADD_F32(a1, 0x114);                        \
        DPP_ADD_F32(a2, 0x114); DPP_ADD_F32(a3, 0x114);                        \
        float4 h4_;                                                            \
        h4_.x = fmaxf(a0, 0.0f); h4_.y = fmaxf(a1, 0.0f);                      \
        h4_.z = fmaxf(a2, 0.0f); h4_.w = fmaxf(a3, 0.0f);                      \
        p_carry = 0.0f;                                                        \
        if (wr) {                                                              \
            *(float4*)&hbuf[(RD) ^ 1][hwidx] = h4_;                            \
            p_carry = w4.x * h4_.x + w4.y * h4_.y                              \
                    + w4.z * h4_.z + w4.w * h4_.w;                             \
        }                                                                      \
        t_prev = dir ? (T_LEN - 1 - s_) : s_;                                  \
        chain_barrier_strict();                                                \
    } while (0)

    #pragma unroll 1
    for (int s = 0; s < T_LEN; s += 4) {
        STEP(s,     0, xq0, xq2);
        STEP(s + 1, 1, xq1, xq3);
        STEP(s + 2, 0, xq2, xq0);
        STEP(s + 3, 1, xq3, xq1);
    }
#undef STEP

    {
        float pr = p_carry;
        DPP_ADD_F32(pr, 0x118); DPP_ADD_F32(pr, 0x142); DPP_ADD_F32(pr, 0x143);
        if (l == 63) pout[t_prev] = pr;
    }
}

// ---------------------------------------------------------------------------
// Kernel 3a (sw path): logits from 2 partials (one per direction) + lsm.
// ---------------------------------------------------------------------------
__global__ __launch_bounds__(256)
void brnn_lsm2(const float* __restrict__ part, const float* __restrict__ ws,
               float* __restrict__ out)
{
    const int b   = blockIdx.x;
    const int tid = threadIdx.x;
    __shared__ float lg[T_LEN];
    __shared__ float red[8];

    const float beff = ws[256];

    float lmax = -3.0e38f;
    for (int t = tid; t < T_LEN; t += 256) {
        float s = beff + part[(size_t)b * T_LEN + t]
                       + part[(size_t)(64 + b) * T_LEN + t];
        lg[t] = s;
        lmax = fmaxf(lmax, s);
    }
    #pragma unroll
    for (int mm = 1; mm <= 32; mm <<= 1) lmax = fmaxf(lmax, __shfl_xor(lmax, mm));
    if ((tid & 63) == 0) red[tid >> 6] = lmax;
    __syncthreads();
    const float bmax = fmaxf(fmaxf(red[0], red[1]), fmaxf(red[2], red[3]));

    float lsum = 0.0f;
    for (int t = tid; t < T_LEN; t += 256) lsum += expf(lg[t] - bmax);
    #pragma unroll
    for (int mm = 1; mm <= 32; mm <<= 1) lsum += __shfl_xor(lsum, mm);
    if ((tid & 63) == 0) red[4 + (tid >> 6)] = lsum;
    __syncthreads();
    const float lse = bmax + logf(red[4] + red[5] + red[6] + red[7]);

    for (int t = tid; t < T_LEN; t += 256)
        out[(size_t)b * T_LEN + t] = lg[t] - lse;
}

// ---------------------------------------------------------------------------
// Kernel 3b (fallback path): logits from 8 partials + lsm.
// ---------------------------------------------------------------------------
__global__ __launch_bounds__(256)
void brnn_lsm8(const float* __restrict__ partbuf, const float* __restrict__ ws,
               float* __restrict__ out)
{
    const int b   = blockIdx.x;
    const int tid = threadIdx.x;
    __shared__ float lg[T_LEN];
    __shared__ float red[8];

    const float beff = ws[256];

    float lmax = -3.0e38f;
    for (int t = tid; t < T_LEN; t += 256) {
        float s = beff;
        #pragma unroll
        for (int dw = 0; dw < 8; ++dw) {
            const int dir = dw >> 2, wv = dw & 3;
            s += partbuf[(((size_t)(dir * 64 + b)) * 4 + wv) * T_LEN + t];
        }
        lg[t] = s;
        lmax = fmaxf(lmax, s);
    }
    #pragma unroll
    for (int mm = 1; mm <= 32; mm <<= 1) lmax = fmaxf(lmax, __shfl_xor(lmax, mm));
    if ((tid & 63) == 0) red[tid >> 6] = lmax;
    __syncthreads();
    const float bmax = fmaxf(fmaxf(red[0], red[1]), fmaxf(red[2], red[3]));

    float lsum = 0.0f;
    for (int t = tid; t < T_LEN; t += 256) lsum += expf(lg[t] - bmax);
    #pragma unroll
    for (int mm = 1; mm <= 32; mm <<= 1) lsum += __shfl_xor(lsum, mm);
    if ((tid & 63) == 0) red[4 + (tid >> 6)] = lsum;
    __syncthreads();
    const float lse = bmax + logf(red[4] + red[5] + red[6] + red[7]);

    for (int t = tid; t < T_LEN; t += 256)
        out[(size_t)b * T_LEN + t] = lg[t] - lse;
}

// ---------------------------------------------------------------------------
extern "C" void kernel_launch(void* const* d_in, const int* in_sizes, int n_in,
                              void* d_out, int out_size, void* d_ws, size_t ws_size,
                              hipStream_t stream)
{
    const float* x     = (const float*)d_in[0];
    const float* Wih_f = (const float*)d_in[1];
    const float* Whh_f = (const float*)d_in[2];
    const float* bih_f = (const float*)d_in[3];
    const float* bhh_f = (const float*)d_in[4];
    const float* Wih_b = (const float*)d_in[5];
    const float* Whh_b = (const float*)d_in[6];
    const float* bih_b = (const float*)d_in[7];
    const float* bhh_b = (const float*)d_in[8];
    const float* fc1_W = (const float*)d_in[9];
    const float* fc1_b = (const float*)d_in[10];
    const float* fc2_W = (const float*)d_in[11];
    const float* fc2_b = (const float*)d_in[12];
    float* out = (float*)d_out;

    float* wsf = (float*)d_ws;
    const size_t part_off   = 512;
    const size_t part_elems = (size_t)2 * 64 * 4 * T_LEN;          // 1 Mi floats
    const size_t xp_off     = part_off + part_elems;
    const size_t xp_elems   = (size_t)2 * 64 * T_LEN * H_SZ;       // 32 Mi floats
    float* part = wsf + part_off;
    float* xpbf = wsf + xp_off;
    const bool big_ws = ws_size >= (xp_off + xp_elems) * sizeof(float);

    hipLaunchKernelGGL(prep_kernel, dim3(1), dim3(256), 0, stream,
                       fc1_W, fc1_b, fc2_W, fc2_b, wsf);
    if (big_ws) {
        hipLaunchKernelGGL(xp_gemm, dim3(4096), dim3(256), 0, stream,
                           x, Wih_f, bih_f, bhh_f, Wih_b, bih_b, bhh_b, xpbf);
        hipLaunchKernelGGL(brnn_recur_sw, dim3(128), dim3(64), 0, stream,
                           xpbf, Whh_f, Whh_b, wsf, part);
        hipLaunchKernelGGL(brnn_lsm2, dim3(64), dim3(256), 0, stream,
                           part, wsf, out);
    } else {
        hipLaunchKernelGGL(brnn_recur_fb, dim3(128), dim3(256), 0, stream,
                           x, Wih_f, Whh_f, bih_f, bhh_f,
                           Wih_b, Whh_b, bih_b, bhh_b, wsf, part);
        hipLaunchKernelGGL(brnn_lsm8, dim3(64), dim3(256), 0, stream,
                           part, wsf, out);
    }
}

// Round 13
// 704.518 us; speedup vs baseline: 3.4413x; 2.7596x over previous
//
#include <hip/hip_runtime.h>
#include <hip/hip_bf16.h>

#define T_LEN 2048
#define B_SZ  64
#define D_IN  64
#define H_SZ  128

// ---------------------------------------------------------------------------
// Kernel 1b (v3-jt, proven r10) + prep merged in as block 4096:
//   blocks 0..4095: xp[(dir*64+b)][j][t] = x·Wih^T + bih + bhh
//   block  4096   : w_eff[256], b_eff  (fc1/fc2 collapse)
// ws layout (floats): [0..255]=w_eff, [256]=b_eff, [512..]=partials, then xp
// ---------------------------------------------------------------------------
__global__ __launch_bounds__(256, 2)
void xp_gemm(const float* __restrict__ x,
             const float* __restrict__ Wih_f, const float* __restrict__ bih_f,
             const float* __restrict__ bhh_f,
             const float* __restrict__ Wih_b, const float* __restrict__ bih_b,
             const float* __restrict__ bhh_b,
             const float* __restrict__ fc1_W, const float* __restrict__ fc1_b,
             const float* __restrict__ fc2_W, const float* __restrict__ fc2_b,
             float* __restrict__ ws, float* __restrict__ xp)
{
    const int blk = blockIdx.x;
    const int tid = threadIdx.x;

    __shared__ __align__(16) float xs[64][68];
    __shared__ __align__(16) float wsd[128][68];
    __shared__ float bs[128];

    if (blk == 4096) {   // prep: collapse fc1+fc2 (no nonlinearity between)
        float s = 0.0f;
        #pragma unroll 4
        for (int o = 0; o < 128; ++o) s = fmaf(fc2_W[o], fc1_W[o * 256 + tid], s);
        ws[tid] = s;
        if (tid < 128) bs[tid] = fc2_W[tid] * fc1_b[tid];
        __syncthreads();
        if (tid == 0) {
            float b = fc2_b[0];
            for (int o = 0; o < 128; ++o) b += bs[o];
            ws[256] = b;
        }
        return;
    }

    const int dir = blk >> 11;
    const int b   = (blk >> 5) & 63;
    const int tc  = blk & 31;

    const float* __restrict__ Wih = dir ? Wih_b : Wih_f;
    const float* __restrict__ bih = dir ? bih_b : bih_f;
    const float* __restrict__ bhh = dir ? bhh_b : bhh_f;

    {
        const float4* src = (const float4*)(x + ((size_t)b * T_LEN + tc * 64) * D_IN);
        #pragma unroll
        for (int r = 0; r < 4; ++r) {
            int qq = tid + 256 * r;
            float4 v = src[qq];
            *(float4*)&xs[qq >> 4][(qq & 15) * 4] = v;
        }
        const float4* wsrc = (const float4*)Wih;
        #pragma unroll
        for (int r = 0; r < 8; ++r) {
            int qq = tid + 256 * r;
            float4 v = wsrc[qq];
            *(float4*)&wsd[qq >> 4][(qq & 15) * 4] = v;
        }
        if (tid < 128) bs[tid] = bih[tid] + bhh[tid];
    }
    __syncthreads();

    const int tg = tid & 15;   // t = tc*64 + tg + 16*tt
    const int jg = tid >> 4;   // j = jg + 16*jj

    float acc[8][4];
    #pragma unroll
    for (int jj = 0; jj < 8; ++jj)
        #pragma unroll
        for (int tt = 0; tt < 4; ++tt) acc[jj][tt] = 0.0f;

    #pragma unroll 2
    for (int kc = 0; kc < 16; ++kc) {
        float4 xv[4];
        #pragma unroll
        for (int tt = 0; tt < 4; ++tt)
            xv[tt] = *(const float4*)&xs[tg + 16 * tt][kc * 4];
        #pragma unroll
        for (int jj = 0; jj < 8; ++jj) {
            float4 wv = *(const float4*)&wsd[jg + 16 * jj][kc * 4];
            #pragma unroll
            for (int tt = 0; tt < 4; ++tt) {
                acc[jj][tt] = fmaf(wv.x, xv[tt].x, acc[jj][tt]);
                acc[jj][tt] = fmaf(wv.y, xv[tt].y, acc[jj][tt]);
                acc[jj][tt] = fmaf(wv.z, xv[tt].z, acc[jj][tt]);
                acc[jj][tt] = fmaf(wv.w, xv[tt].w, acc[jj][tt]);
            }
        }
    }

    float* xpo = xp + (size_t)(dir * 64 + b) * H_SZ * T_LEN + tc * 64 + tg;
    #pragma unroll
    for (int jj = 0; jj < 8; ++jj) {
        const float bj = bs[jg + 16 * jj];
        #pragma unroll
        for (int tt = 0; tt < 4; ++tt)
            xpo[(size_t)(jg + 16 * jj) * T_LEN + 16 * tt] = acc[jj][tt] + bj;
    }
}

// Standalone prep for the fallback path.
__global__ __launch_bounds__(256)
void prep_kernel(const float* __restrict__ fc1_W, const float* __restrict__ fc1_b,
                 const float* __restrict__ fc2_W, const float* __restrict__ fc2_b,
                 float* __restrict__ ws)
{
    const int i = threadIdx.x;
    float s = 0.0f;
    #pragma unroll 4
    for (int o = 0; o < 128; ++o) s = fmaf(fc2_W[o], fc1_W[o * 256 + i], s);
    ws[i] = s;

    __shared__ float red[128];
    if (i < 128) red[i] = fc2_W[i] * fc1_b[i];
    __syncthreads();
    if (i == 0) {
        float b = fc2_b[0];
        for (int o = 0; o < 128; ++o) b += red[o];
        ws[256] = b;
    }
}

// DPP add: v += dpp_moved(v); bound_ctrl=true -> invalid source lanes give 0.
#define DPP_ADD_F32(v, ctrl)                                                   \
    v += __int_as_float(__builtin_amdgcn_update_dpp(                           \
            0, __float_as_int(v), (ctrl), 0xf, 0xf, true))

// Relaxed barrier: lgkmcnt(0) (ds visibility) without the vmcnt(0) drain.
__device__ __forceinline__ void chain_barrier() {
    asm volatile("s_waitcnt lgkmcnt(0)" ::: "memory");
    __builtin_amdgcn_s_barrier();
    asm volatile("" ::: "memory");
}
__device__ __forceinline__ void chain_barrier_strict() {
    asm volatile("s_waitcnt lgkmcnt(0)" ::: "memory");
    __builtin_amdgcn_s_barrier();
    __builtin_amdgcn_sched_barrier(0);
}

// h LDS layout: float k stored at index k + 4*(k>>4)  (80B row stride).
// Group g (k = 16g..+15) = 16 contiguous floats at idx 20g -> bank
// starts {0,20,8,28,16,4,24,12} -> conflict-free b128 reads.

// ---------------------------------------------------------------------------
// Kernel 2 (round-6/10 verbatim, measured 656us twice): ReLU recurrence +
// logit partial dot, DIR-templated. One block per (dir,batch): 128 blocks,
// 256 threads, 1 wave/SIMD. 16-step outer body, two 8-slot xp register
// banks (distance-8 prefetch), p burst-stored as 2x dwordx4 per 8 steps.
// Step ~770 cy = ~200 issue + ~570 cross-wave LDS/barrier turnaround
// (sequential-latency floor; 5 structural removal attempts all regressed).
// ---------------------------------------------------------------------------
template<int DIR>
__device__ __forceinline__
void recur_chain(const float* __restrict__ xp, const float* __restrict__ Whh,
                 const float* __restrict__ weff, float* __restrict__ partbuf,
                 int b, int blk, float (*hbuf)[160])
{
    const int tid = threadIdx.x;
    const int w   = tid >> 6;
    const int l   = tid & 63;
    const int g   = l & 7;
    const int m   = l >> 3;
    const int j0  = w * 32 + m * 4;
    const bool wr = (g == 7);

    float whh[64];
    #pragma unroll
    for (int jj = 0; jj < 4; ++jj)
        #pragma unroll
        for (int i = 0; i < 4; ++i)
            ((float4*)whh)[jj * 4 + i] =
                *(const float4*)(Whh + (j0 + jj) * H_SZ + g * 16 + i * 4);

    const float4 w4 = *(const float4*)(weff + DIR * H_SZ + j0);

    const float4* rd0 = (const float4*)&hbuf[0][20 * g];
    const float4* rd1 = (const float4*)&hbuf[1][20 * g];
    const int hwidx = 40 * w + 4 * m + 4 * (m >> 2);
    float* wp1 = &hbuf[1][hwidx];   // even steps read buf0, write buf1
    float* wp0 = &hbuf[0][hwidx];

    const size_t rowbase = ((size_t)(DIR * 64 + b) * H_SZ + j0) * (size_t)T_LEN;
    const int t0 = DIR ? (T_LEN - 1) : 0;
    const float* xs0 = xp + rowbase + (size_t)0 * T_LEN + t0;
    const float* xs1 = xp + rowbase + (size_t)1 * T_LEN + t0;
    const float* xs2 = xp + rowbase + (size_t)2 * T_LEN + t0;
    const float* xs3 = xp + rowbase + (size_t)3 * T_LEN + t0;

    float* pst = partbuf + ((size_t)blk * 4 + w) * T_LEN + (DIR ? (T_LEN - 8) : 0);

    float4 XA[8], XB[8];
    #pragma unroll
    for (int k = 0; k < 8; ++k) {
        const int o = DIR ? -k : k;
        XA[k].x = xs0[o]; XA[k].y = xs1[o]; XA[k].z = xs2[o]; XA[k].w = xs3[o];
    }
    const ptrdiff_t adv = DIR ? -8 : 8;
    xs0 += adv; xs1 += adv; xs2 += adv; xs3 += adv;

    float ps[8];

#define KSTEP(K, XCUR, XNXT) do {                                              \
        float4 hv0, hv1, hv2, hv3;                                             \
        if ((K) & 1) { hv0 = rd1[0]; hv1 = rd1[1]; hv2 = rd1[2]; hv3 = rd1[3]; } \
        else         { hv0 = rd0[0]; hv1 = rd0[1]; hv2 = rd0[2]; hv3 = rd0[3]; } \
        {   /* prefetch this slot for the NEXT iteration (8 steps ahead) */    \
            const int o_ = DIR ? -(K) : (K);                                   \
            XNXT[K].x = xs0[o_]; XNXT[K].y = xs1[o_];                          \
            XNXT[K].z = xs2[o_]; XNXT[K].w = xs3[o_];                          \
        }                                                                      \
        float a0 = (g == 0) ? XCUR[K].x : 0.0f;                                \
        float a1 = (g == 0) ? XCUR[K].y : 0.0f;                                \
        float a2 = (g == 0) ? XCUR[K].z : 0.0f;                                \
        float a3 = (g == 0) ? XCUR[K].w : 0.0f;                                \
        _Pragma("unroll") for (int c = 0; c < 4; ++c) {                        \
            const float h_ = ((const float*)&hv0)[c];                          \
            a0 = fmaf(whh[ 0 + c], h_, a0); a1 = fmaf(whh[16 + c], h_, a1);    \
            a2 = fmaf(whh[32 + c], h_, a2); a3 = fmaf(whh[48 + c], h_, a3);    \
        }                                                                      \
        _Pragma("unroll") for (int c = 0; c < 4; ++c) {                        \
            const float h_ = ((const float*)&hv1)[c];                          \
            a0 = fmaf(whh[ 4 + c], h_, a0); a1 = fmaf(whh[20 + c], h_, a1);    \
            a2 = fmaf(whh[36 + c], h_, a2); a3 = fmaf(whh[52 + c], h_, a3);    \
        }                                                                      \
        _Pragma("unroll") for (int c = 0; c < 4; ++c) {                        \
            const float h_ = ((const float*)&hv2)[c];                          \
            a0 = fmaf(whh[ 8 + c], h_, a0); a1 = fmaf(whh[24 + c], h_, a1);    \
            a2 = fmaf(whh[40 + c], h_, a2); a3 = fmaf(whh[56 + c], h_, a3);    \
        }                                                                      \
        _Pragma("unroll") for (int c = 0; c < 4; ++c) {                        \
            const float h_ = ((const float*)&hv3)[c];                          \
            a0 = fmaf(whh[12 + c], h_, a0); a1 = fmaf(whh[28 + c], h_, a1);    \
            a2 = fmaf(whh[44 + c], h_, a2); a3 = fmaf(whh[60 + c], h_, a3);    \
        }                                                                      \
        DPP_ADD_F32(a0, 0x111); DPP_ADD_F32(a1, 0x111);                        \
        DPP_ADD_F32(a2, 0x111); DPP_ADD_F32(a3, 0x111);                        \
        DPP_ADD_F32(a0, 0x112); DPP_ADD_F32(a1, 0x112);                        \
        DPP_ADD_F32(a2, 0x112); DPP_ADD_F32(a3, 0x112);                        \
        DPP_ADD_F32(a0, 0x114); DPP_ADD_F32(a1, 0x114);                        \
        DPP_ADD_F32(a2, 0x114); DPP_ADD_F32(a3, 0x114);                        \
        float4 h4;                                                             \
        h4.x = fmaxf(a0, 0.0f); h4.y = fmaxf(a1, 0.0f);                        \
        h4.z = fmaxf(a2, 0.0f); h4.w = fmaxf(a3, 0.0f);                        \
        if (wr) *(float4*)(((K) & 1) ? wp0 : wp1) = h4;                        \
        float pv = wr ? (w4.x * h4.x + w4.y * h4.y                             \
                       + w4.z * h4.z + w4.w * h4.w) : 0.0f;                    \
        DPP_ADD_F32(pv, 0x118); DPP_ADD_F32(pv, 0x142); DPP_ADD_F32(pv, 0x143);\
        ps[K] = pv;                                                            \
        chain_barrier();                                                       \
    } while (0)

#define ITER8(XCUR, XNXT) do {                                                 \
        KSTEP(0, XCUR, XNXT); KSTEP(1, XCUR, XNXT);                            \
        KSTEP(2, XCUR, XNXT); KSTEP(3, XCUR, XNXT);                            \
        KSTEP(4, XCUR, XNXT); KSTEP(5, XCUR, XNXT);                            \
        KSTEP(6, XCUR, XNXT); KSTEP(7, XCUR, XNXT);                            \
        if (l == 63) {                                                         \
            float4 v0, v1;                                                     \
            if (DIR) { v0 = make_float4(ps[7], ps[6], ps[5], ps[4]);           \
                       v1 = make_float4(ps[3], ps[2], ps[1], ps[0]); }         \
            else     { v0 = make_float4(ps[0], ps[1], ps[2], ps[3]);           \
                       v1 = make_float4(ps[4], ps[5], ps[6], ps[7]); }         \
            *(float4*)pst = v0; *(float4*)(pst + 4) = v1;                      \
        }                                                                      \
        xs0 += adv; xs1 += adv; xs2 += adv; xs3 += adv;                        \
        pst += DIR ? -8 : 8;                                                   \
    } while (0)

    #pragma unroll 1
    for (int it = 0; it < T_LEN / 16; ++it) {
        ITER8(XA, XB);
        ITER8(XB, XA);
    }
#undef ITER8
#undef KSTEP
}

__global__ __launch_bounds__(256, 1)
void brnn_recur_xp(const float* __restrict__ xp,
                   const float* __restrict__ Whh_f, const float* __restrict__ Whh_b,
                   const float* __restrict__ weff,  float* __restrict__ partbuf)
{
    __shared__ __align__(16) float hbuf[2][160];
    const int blk = blockIdx.x;
    const int dir = blk >> 6;
    const int b   = blk & 63;
    if (threadIdx.x < 160) hbuf[0][threadIdx.x] = 0.0f;
    __syncthreads();
    if (dir == 0) recur_chain<0>(xp, Whh_f, weff, partbuf, b, blk, hbuf);
    else          recur_chain<1>(xp, Whh_b, weff, partbuf, b, blk, hbuf);
}

// ---------------------------------------------------------------------------
// Fallback recurrence (round-4 structure, x in-loop) for small ws_size.
// ---------------------------------------------------------------------------
__global__ __launch_bounds__(256, 1)
void brnn_recur_fb(const float* __restrict__ x,
                   const float* __restrict__ Wih_f, const float* __restrict__ Whh_f,
                   const float* __restrict__ bih_f, const float* __restrict__ bhh_f,
                   const float* __restrict__ Wih_b, const float* __restrict__ Whh_b,
                   const float* __restrict__ bih_b, const float* __restrict__ bhh_b,
                   const float* __restrict__ weff,  float* __restrict__ partbuf)
{
    const int blk  = blockIdx.x;
    const int dir  = blk >> 6;
    const int b    = blk & 63;
    const int tid  = threadIdx.x;
    const int w    = tid >> 6;
    const int l    = tid & 63;
    const int g    = l & 7;
    const int m    = l >> 3;
    const int j0   = w * 32 + m * 4;
    const bool wr  = (g == 7);

    const float* Wih = dir ? Wih_b : Wih_f;
    const float* Whh = dir ? Whh_b : Whh_f;
    const float* bih = dir ? bih_b : bih_f;
    const float* bhh = dir ? bhh_b : bhh_f;

    float whh[64];
    #pragma unroll
    for (int jj = 0; jj < 4; ++jj)
        #pragma unroll
        for (int i = 0; i < 4; ++i)
            ((float4*)whh)[jj * 4 + i] =
                *(const float4*)(Whh + (j0 + jj) * 128 + g * 16 + i * 4);
    float wih[32];
    #pragma unroll
    for (int jj = 0; jj < 4; ++jj)
        #pragma unroll
        for (int i = 0; i < 2; ++i)
            ((float4*)wih)[jj * 2 + i] =
                *(const float4*)(Wih + (j0 + jj) * 64 + g * 8 + i * 4);

    float4 b4 = make_float4(0.f, 0.f, 0.f, 0.f);
    if (g == 0) {
        float4 bi = *(const float4*)(bih + j0);
        float4 bh = *(const float4*)(bhh + j0);
        b4 = make_float4(bi.x + bh.x, bi.y + bh.y, bi.z + bh.z, bi.w + bh.w);
    }
    const float4 w4 = *(const float4*)(weff + dir * 128 + j0);

    __shared__ __align__(16) float hbuf[2][160];
    if (tid < 160) hbuf[0][tid] = 0.0f;
    __syncthreads();

    const float* xbase = x + (size_t)b * T_LEN * D_IN + g * 8;
    float* pout = partbuf + ((size_t)blk * 4 + w) * T_LEN;

    float xq0[8], xq1[8], xq2[8], xq3[8];
    {
        const float4* xp0 = (const float4*)(xbase + (size_t)(dir ? (T_LEN - 1) : 0) * D_IN);
        ((float4*)xq0)[0] = xp0[0];
        ((float4*)xq0)[1] = xp0[1];
        const float4* xp1 = (const float4*)(xbase + (size_t)(dir ? (T_LEN - 2) : 1) * D_IN);
        ((float4*)xq1)[0] = xp1[0];
        ((float4*)xq1)[1] = xp1[1];
    }

    float p_carry = 0.0f;
    int   t_prev  = 0;
    const int hwidx = 40 * w + 4 * m + 4 * (m >> 2);

#define STEP(S, RD, XCUR, XPRE) do {                                           \
        const int s_  = (S);                                                   \
        if (s_ > 0) {                                                          \
            float pr_ = p_carry;                                               \
            DPP_ADD_F32(pr_, 0x118); DPP_ADD_F32(pr_, 0x142);                  \
            DPP_ADD_F32(pr_, 0x143);                                           \
            if (l == 63) pout[t_prev] = pr_;                                   \
        }                                                                      \
        {                                                                      \
            const int sp_ = (s_ + 2 < T_LEN) ? (s_ + 2) : (T_LEN - 1);         \
            const int tp_ = dir ? (T_LEN - 1 - sp_) : sp_;                     \
            const float4* xp_ = (const float4*)(xbase + (size_t)tp_ * D_IN);   \
            ((float4*)XPRE)[0] = xp_[0];                                       \
            ((float4*)XPRE)[1] = xp_[1];                                       \
        }                                                                      \
        const float4* hp_ = (const float4*)&hbuf[RD][20 * g];                  \
        float4 hv_[4];                                                         \
        _Pragma("unroll") for (int i = 0; i < 4; ++i) hv_[i] = hp_[i];         \
        float a0 = b4.x, a1 = b4.y, a2 = b4.z, a3 = b4.w;                      \
        _Pragma("unroll") for (int i = 0; i < 8; ++i) {                        \
            a0 = fmaf(wih[0 * 8 + i], XCUR[i], a0);                            \
            a1 = fmaf(wih[1 * 8 + i], XCUR[i], a1);                            \
            a2 = fmaf(wih[2 * 8 + i], XCUR[i], a2);                            \
            a3 = fmaf(wih[3 * 8 + i], XCUR[i], a3);                            \
        }                                                                      \
        _Pragma("unroll") for (int i = 0; i < 4; ++i) {                        \
            const float* hq_ = (const float*)&hv_[i];                          \
            _Pragma("unroll") for (int c = 0; c < 4; ++c) {                    \
                a0 = fmaf(whh[0 * 16 + i * 4 + c], hq_[c], a0);                \
                a1 = fmaf(whh[1 * 16 + i * 4 + c], hq_[c], a1);                \
                a2 = fmaf(whh[2 * 16 + i * 4 + c], hq_[c], a2);                \
                a3 = fmaf(whh[3 * 16 + i * 4 + c], hq_[c], a3);                \
            }                                                                  \
        }                                                                      \
        DPP_ADD_F32(a0, 0x111); DPP_ADD_F32(a1, 0x111);                        \
        DPP_ADD_F32(a2, 0x111); DPP_ADD_F32(a3, 0x111);                        \
        DPP_ADD_F32(a0, 0x112); DPP_ADD_F32(a1, 0x112);                        \
        DPP_ADD_F32(a2, 0x112); DPP_ADD_F32(a3, 0x112);                        \
        DPP_ADD_F32(a0, 0x114); DPP_ADD_F32(a1, 0x114);                        \
        DPP_ADD_F32(a2, 0x114); DPP_ADD_F32(a3, 0x114);                        \
        float4 h4_;                                                            \
        h4_.x = fmaxf(a0, 0.0f); h4_.y = fmaxf(a1, 0.0f);                      \
        h4_.z = fmaxf(a2, 0.0f); h4_.w = fmaxf(a3, 0.0f);                      \
        p_carry = 0.0f;                                                        \
        if (wr) {                                                              \
            *(float4*)&hbuf[(RD) ^ 1][hwidx] = h4_;                            \
            p_carry = w4.x * h4_.x + w4.y * h4_.y                              \
                    + w4.z * h4_.z + w4.w * h4_.w;                             \
        }                                                                      \
        t_prev = dir ? (T_LEN - 1 - s_) : s_;                                  \
        chain_barrier_strict();                                                \
    } while (0)

    #pragma unroll 1
    for (int s = 0; s < T_LEN; s += 4) {
        STEP(s,     0, xq0, xq2);
        STEP(s + 1, 1, xq1, xq3);
        STEP(s + 2, 0, xq2, xq0);
        STEP(s + 3, 1, xq3, xq1);
    }
#undef STEP

    {
        float pr = p_carry;
        DPP_ADD_F32(pr, 0x118); DPP_ADD_F32(pr, 0x142); DPP_ADD_F32(pr, 0x143);
        if (l == 63) pout[t_prev] = pr;
    }
}

// ---------------------------------------------------------------------------
// Kernel 3: assemble logits from 8 partials and log-softmax over T per batch.
// ---------------------------------------------------------------------------
__global__ __launch_bounds__(256)
void brnn_lsm(const float* __restrict__ partbuf, const float* __restrict__ ws,
              float* __restrict__ out)
{
    const int b   = blockIdx.x;
    const int tid = threadIdx.x;
    __shared__ float lg[T_LEN];
    __shared__ float red[8];

    const float beff = ws[256];

    float lmax = -3.0e38f;
    for (int t = tid; t < T_LEN; t += 256) {
        float s = beff;
        #pragma unroll
        for (int dw = 0; dw < 8; ++dw) {
            const int dir = dw >> 2, wv = dw & 3;
            s += partbuf[(((size_t)(dir * 64 + b)) * 4 + wv) * T_LEN + t];
        }
        lg[t] = s;
        lmax = fmaxf(lmax, s);
    }
    #pragma unroll
    for (int mm = 1; mm <= 32; mm <<= 1) lmax = fmaxf(lmax, __shfl_xor(lmax, mm));
    if ((tid & 63) == 0) red[tid >> 6] = lmax;
    __syncthreads();
    const float bmax = fmaxf(fmaxf(red[0], red[1]), fmaxf(red[2], red[3]));

    float lsum = 0.0f;
    for (int t = tid; t < T_LEN; t += 256) lsum += expf(lg[t] - bmax);
    #pragma unroll
    for (int mm = 1; mm <= 32; mm <<= 1) lsum += __shfl_xor(lsum, mm);
    if ((tid & 63) == 0) red[4 + (tid >> 6)] = lsum;
    __syncthreads();
    const float lse = bmax + logf(red[4] + red[5] + red[6] + red[7]);

    for (int t = tid; t < T_LEN; t += 256)
        out[(size_t)b * T_LEN + t] = lg[t] - lse;
}

// ---------------------------------------------------------------------------
extern "C" void kernel_launch(void* const* d_in, const int* in_sizes, int n_in,
                              void* d_out, int out_size, void* d_ws, size_t ws_size,
                              hipStream_t stream)
{
    const float* x     = (const float*)d_in[0];
    const float* Wih_f = (const float*)d_in[1];
    const float* Whh_f = (const float*)d_in[2];
    const float* bih_f = (const float*)d_in[3];
    const float* bhh_f = (const float*)d_in[4];
    const float* Wih_b = (const float*)d_in[5];
    const float* Whh_b = (const float*)d_in[6];
    const float* bih_b = (const float*)d_in[7];
    const float* bhh_b = (const float*)d_in[8];
    const float* fc1_W = (const float*)d_in[9];
    const float* fc1_b = (const float*)d_in[10];
    const float* fc2_W = (const float*)d_in[11];
    const float* fc2_b = (const float*)d_in[12];
    float* out = (float*)d_out;

    float* wsf = (float*)d_ws;
    const size_t part_off   = 512;
    const size_t part_elems = (size_t)2 * 64 * 4 * T_LEN;          // 1 Mi floats
    const size_t xp_off     = part_off + part_elems;
    const size_t xp_elems   = (size_t)2 * 64 * T_LEN * H_SZ;       // 32 Mi floats
    float* part = wsf + part_off;
    float* xpbf = wsf + xp_off;
    const bool big_ws = ws_size >= (xp_off + xp_elems) * sizeof(float);

    if (big_ws) {
        hipLaunchKernelGGL(xp_gemm, dim3(4097), dim3(256), 0, stream,
                           x, Wih_f, bih_f, bhh_f, Wih_b, bih_b, bhh_b,
                           fc1_W, fc1_b, fc2_W, fc2_b, wsf, xpbf);
        hipLaunchKernelGGL(brnn_recur_xp, dim3(128), dim3(256), 0, stream,
                           xpbf, Whh_f, Whh_b, wsf, part);
    } else {
        hipLaunchKernelGGL(prep_kernel, dim3(1), dim3(256), 0, stream,
                           fc1_W, fc1_b, fc2_W, fc2_b, wsf);
        hipLaunchKernelGGL(brnn_recur_fb, dim3(128), dim3(256), 0, stream,
                           x, Wih_f, Whh_f, bih_f, bhh_f,
                           Wih_b, Whh_b, bih_b, bhh_b, wsf, part);
    }
    hipLaunchKernelGGL(brnn_lsm, dim3(64), dim3(256), 0, stream,
                       part, wsf, out);
}